// Round 5
// baseline (58.296 us; speedup 1.0000x reference)
//
#include <hip/hip_runtime.h>
#include <math.h>

// KAN layer fused kernel for MI355X (gfx950), round 5.
// BATCH=32768, IN_FEATURES=64, GRID=64, WIDTH=64, DEGREE=3, clamped uniform knots.
//
// Key change vs r4: pre-WINDOWED int8 coeff table win[f][g0][w] = 4 packed taps
// c[g0..g0+3][w] (x512, int8). The per-(row,w) 4-tap contraction becomes ONE
// v_dot4_i32_i8; gather is 2x ds_read_b128 of 8 contiguous window dwords.
// Slab rows padded to 272B (16B aligned, 4-bank rotation). Staging via
// global_load_lds width=16, double-buffered, 1 barrier/f.

#define NTHREADS 512
#define ROWS 64
#define WROW 272              // window slab row stride (bytes), 61 rows used
#define SLABB 16640           // 61*272=16592 rounded up to 16B multiple (1040 chunks)

typedef float v2f __attribute__((ext_vector_type(2)));

#if __has_builtin(__builtin_amdgcn_sdot4)
#define SDOT4(a, b, c) __builtin_amdgcn_sdot4((int)(a), (int)(b), (c), false)
#else
__device__ __forceinline__ int sdot4_sw(unsigned a, unsigned b, int c) {
    return c + (int)(signed char)(a) * (int)(signed char)(b)
             + (int)(signed char)(a >> 8)  * (int)(signed char)(b >> 8)
             + (int)(signed char)(a >> 16) * (int)(signed char)(b >> 16)
             + (int)(signed char)(a >> 24) * (int)(signed char)(b >> 24);
}
#define SDOT4(a, b, c) sdot4_sw((a), (b), (c))
#endif

__device__ __forceinline__ unsigned int f2bf1(float f) {
    unsigned int u = __float_as_uint(f);
    return (u + 0x7fffu + ((u >> 16) & 1u)) >> 16;   // RNE bf16
}
__device__ __forceinline__ v2f up2(unsigned int u) {   // 2x bf16 -> 2x f32
    v2f r;
    r.x = __uint_as_float(u << 16);
    r.y = __uint_as_float(u & 0xffff0000u);
    return r;
}
__device__ __forceinline__ unsigned int q8(float v) {  // int8(x512) clamp, low byte
    const float s = fminf(fmaxf(v * 512.f, -127.f), 127.f);
    return (unsigned int)((int)rintf(s)) & 255u;
}

// prep: coeff f32 [64][64][64] -> windowed int8 image ws[f][g0*272 + w*4]
__global__ __launch_bounds__(256) void kan_prep(
    const float* __restrict__ coeff_g,
    unsigned char* __restrict__ ws8)
{
    __shared__ unsigned char raw[4096];     // int8 [g][w]
    const int f = blockIdx.x;               // 64
    const int t = threadIdx.x;              // 256
    {   // quantize 16 coeffs/thread
        const float* src = coeff_g + (size_t)f * 4096 + t * 16;
        const float4 a0 = ((const float4*)src)[0];
        const float4 a1 = ((const float4*)src)[1];
        const float4 a2 = ((const float4*)src)[2];
        const float4 a3 = ((const float4*)src)[3];
        uint4 p;
        p.x = q8(a0.x) | (q8(a0.y) << 8) | (q8(a0.z) << 16) | (q8(a0.w) << 24);
        p.y = q8(a1.x) | (q8(a1.y) << 8) | (q8(a1.z) << 16) | (q8(a1.w) << 24);
        p.z = q8(a2.x) | (q8(a2.y) << 8) | (q8(a2.z) << 16) | (q8(a2.w) << 24);
        p.w = q8(a3.x) | (q8(a3.y) << 8) | (q8(a3.z) << 16) | (q8(a3.w) << 24);
        ((uint4*)raw)[t] = p;
    }
    __syncthreads();
    unsigned char* dst = ws8 + (size_t)f * SLABB;
    #pragma unroll
    for (int i = 0; i < 16; ++i) {          // 61*64 = 3904 window dwords
        const int idx = i * 256 + t;
        if (idx < 3904) {
            const int g0 = idx >> 6, w = idx & 63;
            const unsigned int d = (unsigned int)raw[g0 * 64 + w]
                                 | ((unsigned int)raw[(g0 + 1) * 64 + w] << 8)
                                 | ((unsigned int)raw[(g0 + 2) * 64 + w] << 16)
                                 | ((unsigned int)raw[(g0 + 3) * 64 + w] << 24);
            *(unsigned int*)(dst + g0 * WROW + w * 4) = d;
        }
    }
}

template<bool PRE>
__global__ __launch_bounds__(NTHREADS, 4) void kan_fused(
    const float* __restrict__ x_g,      // [32768][64]
    const float* __restrict__ shift_g,  // [64]
    const float* __restrict__ lsc_g,    // [64]
    const float* __restrict__ coeff_g,  // [64][64][64] (f,g,w)
    const float* __restrict__ skipW_g,  // [64][64] (w,f)
    const float* __restrict__ skipb_g,  // [64]
    const float* __restrict__ bias_g,   // [64]
    const float* __restrict__ gamma_g,  // [64]
    const float* __restrict__ beta_g,   // [64]
    const float* __restrict__ knots_g,  // [68]
    const unsigned char* __restrict__ ws8,
    float* __restrict__ out_g)          // [32768][64]
{
    __shared__ float  xin[64][ROWS];                          // 16 KB [f][row]
    __shared__ uint2  wtab2[8 * ROWS];                        // 4 KB  {wpack, rowbase}
    __shared__ unsigned char slab[2][SLABB] __attribute__((aligned(16)));  // 32.5 KB
    __shared__ unsigned short skw[4096];                      // 8 KB bf16 [f][w] (scratch later)
    __shared__ float  knot_s[68];
    __shared__ float  scale_s[64];
    __shared__ float  shift_s[64];

    const int t = threadIdx.x;
    const int row0 = blockIdx.x * ROWS;

    // basis weights for 8 features x 64 rows; one (fc,row) per thread.
    auto basis_phase = [&](int fbase) {
        const int fc_ = t >> 6, r_ = t & 63;
        const int feat = fbase + fc_;
        const float xs = (xin[feat][r_] - shift_s[feat]) * scale_s[feat];
        const float xq = 1.f / (1.f + __expf(-xs));   // sigmoid in [0,1]
        int m = (int)floorf(xq * 61.f);
        m = m < 0 ? 0 : (m > 60 ? 60 : m);
        const int i = m + 3;
        float left[4], right[4], N[4];
        N[0] = 1.f;
        #pragma unroll
        for (int j = 1; j <= 3; ++j) {
            left[j]  = xq - knot_s[i + 1 - j];
            right[j] = knot_s[i + j] - xq;
            float saved = 0.f;
            #pragma unroll
            for (int rr = 0; rr < j; ++rr) {
                const float temp = N[rr] * __builtin_amdgcn_rcpf(right[rr + 1] + left[j - rr]);
                N[rr] = saved + right[rr + 1] * temp;
                saved = left[j - rr] * temp;
            }
            N[j] = saved;
        }
        // quantize weights to int8 x126 and pack
        const unsigned int w0 = (unsigned int)(int)(fmaxf(N[0], 0.f) * 126.f + 0.5f);
        const unsigned int w1 = (unsigned int)(int)(fmaxf(N[1], 0.f) * 126.f + 0.5f);
        const unsigned int w2 = (unsigned int)(int)(fmaxf(N[2], 0.f) * 126.f + 0.5f);
        const unsigned int w3 = (unsigned int)(int)(fmaxf(N[3], 0.f) * 126.f + 0.5f);
        wtab2[t] = make_uint2(w0 | (w1 << 8) | (w2 << 16) | (w3 << 24),
                              (unsigned int)(m * WROW));
    };

    // stage one window slab via global_load_lds (linear, 16B chunks)
    auto stage_pre = [&](int nb, const unsigned char* wsrc) {
        __builtin_amdgcn_global_load_lds((const unsigned int*)(wsrc + t * 16),
                                         (unsigned int*)(&slab[nb][t * 16]), 16, 0, 0);
        __builtin_amdgcn_global_load_lds((const unsigned int*)(wsrc + 8192 + t * 16),
                                         (unsigned int*)(&slab[nb][8192 + t * 16]), 16, 0, 0);
        if (t < 16)
            __builtin_amdgcn_global_load_lds((const unsigned int*)(wsrc + 16384 + t * 16),
                                             (unsigned int*)(&slab[nb][16384 + t * 16]), 16, 0, 0);
    };

    // fallback: quantize+window-build slab for feature f in-kernel
    auto stage_raw_fb = [&](int f) {
        unsigned char* raw = (unsigned char*)skw;   // 4 KB scratch (skw dead after skip pass)
        const float* src = coeff_g + (size_t)f * 4096 + t * 8;
        const float4 a0 = ((const float4*)src)[0];
        const float4 a1 = ((const float4*)src)[1];
        uint2 p;
        p.x = q8(a0.x) | (q8(a0.y) << 8) | (q8(a0.z) << 16) | (q8(a0.w) << 24);
        p.y = q8(a1.x) | (q8(a1.y) << 8) | (q8(a1.z) << 16) | (q8(a1.w) << 24);
        ((uint2*)raw)[t] = p;
    };
    auto build_fb = [&](int nb) {
        const unsigned char* raw = (const unsigned char*)skw;
        #pragma unroll
        for (int i = 0; i < 8; ++i) {
            const int idx = i * 512 + t;
            if (idx < 3904) {
                const int g0 = idx >> 6, w = idx & 63;
                const unsigned int d = (unsigned int)raw[g0 * 64 + w]
                                     | ((unsigned int)raw[(g0 + 1) * 64 + w] << 8)
                                     | ((unsigned int)raw[(g0 + 2) * 64 + w] << 16)
                                     | ((unsigned int)raw[(g0 + 3) * 64 + w] << 24);
                *(unsigned int*)(&slab[nb][g0 * WROW + w * 4]) = d;
            }
        }
    };

    // ---------------- prologue staging ----------------
    {   // inputs: transpose to [f][row]
        const int r = t >> 3, f0 = (t & 7) << 3;
        const float4* src = (const float4*)(x_g + (size_t)(row0 + r) * 64 + f0);
        const float4 a0 = src[0], a1 = src[1];
        xin[f0 + 0][r] = a0.x; xin[f0 + 1][r] = a0.y;
        xin[f0 + 2][r] = a0.z; xin[f0 + 3][r] = a0.w;
        xin[f0 + 4][r] = a1.x; xin[f0 + 5][r] = a1.y;
        xin[f0 + 6][r] = a1.z; xin[f0 + 7][r] = a1.w;
    }
    {   // skip W: read [w][f] coalesced, write bf16 transposed [f][w]
        const int w = t >> 3, f0 = (t & 7) << 3;
        const float4* src = (const float4*)(skipW_g + (size_t)w * 64 + f0);
        const float4 a0 = src[0], a1 = src[1];
        skw[(f0 + 0) * 64 + w] = (unsigned short)f2bf1(a0.x);
        skw[(f0 + 1) * 64 + w] = (unsigned short)f2bf1(a0.y);
        skw[(f0 + 2) * 64 + w] = (unsigned short)f2bf1(a0.z);
        skw[(f0 + 3) * 64 + w] = (unsigned short)f2bf1(a0.w);
        skw[(f0 + 4) * 64 + w] = (unsigned short)f2bf1(a1.x);
        skw[(f0 + 5) * 64 + w] = (unsigned short)f2bf1(a1.y);
        skw[(f0 + 6) * 64 + w] = (unsigned short)f2bf1(a1.z);
        skw[(f0 + 7) * 64 + w] = (unsigned short)f2bf1(a1.w);
    }
    if (t < 64) {
        scale_s[t] = log1pf(__expf(lsc_g[t])) + 0.001f;   // softplus + 0.001
        shift_s[t] = shift_g[t];
    }
    if (t < 68) knot_s[t] = knots_g[t];
    if (PRE) stage_pre(0, ws8);           // DMA slab f=0; overlaps skip pass
    __syncthreads();

    const int lane = t & 63;
    const int wave = t >> 6;        // 0..7
    const int rsub = lane >> 3;     // 0..7
    const int wc   = lane & 7;      // 0..7
    const int w8   = wc << 3;       // widths w8..w8+7
    const int row  = (wave << 3) + rsub;   // 0..63

    // ---------------- skip pass: acc += x[row][f] * W[w][f] (bf16) ----------------
    v2f acc2[4];
    #pragma unroll
    for (int q = 0; q < 4; ++q) acc2[q] = (v2f){0.f, 0.f};
    #pragma unroll 4
    for (int f = 0; f < 64; ++f) {
        const float xv = xin[f][row];
        const uint4 sp = *((const uint4*)(&skw[f * 64 + w8]));
        const v2f xv2 = {xv, xv};
        acc2[0] += xv2 * up2(sp.x);
        acc2[1] += xv2 * up2(sp.y);
        acc2[2] += xv2 * up2(sp.z);
        acc2[3] += xv2 * up2(sp.w);
    }
    basis_phase(0);
    __syncthreads();   // skip reads done; wtab group 0 (+ slab f0 if PRE) visible

    if (!PRE) {        // build slab f=0 in-kernel (skw now scratch)
        stage_raw_fb(0);
        __syncthreads();
        build_fb(0);
        __syncthreads();
    }

    int doti[8];
    #pragma unroll
    for (int k = 0; k < 8; ++k) doti[k] = 0;

    const int wcb = wc << 5;   // byte offset of this thread's 8 window dwords

    // ---------------- main loop over features ----------------
    int buf = 0;
    for (int f = 0; f < 64; ++f) {
        if (PRE && f < 63) stage_pre(buf ^ 1, ws8 + (size_t)(f + 1) * SLABB);
        if (!PRE && f < 63) stage_raw_fb(f + 1);

        // ------- gather + dot4, feature f -------
        {
            const int fc = f & 7;
            const uint2 wv = wtab2[(fc << 6) + row];
            const unsigned char* sp = &slab[buf][wv.y + wcb];
            const uint4 A = *((const uint4*)sp);
            const uint4 B = *((const uint4*)(sp + 16));
            doti[0] = SDOT4(wv.x, A.x, doti[0]);
            doti[1] = SDOT4(wv.x, A.y, doti[1]);
            doti[2] = SDOT4(wv.x, A.z, doti[2]);
            doti[3] = SDOT4(wv.x, A.w, doti[3]);
            doti[4] = SDOT4(wv.x, B.x, doti[4]);
            doti[5] = SDOT4(wv.x, B.y, doti[5]);
            doti[6] = SDOT4(wv.x, B.z, doti[6]);
            doti[7] = SDOT4(wv.x, B.w, doti[7]);
        }

        if ((f & 7) == 7 && f < 63) {
            __syncthreads();          // all reads of current wtab group done
            basis_phase(f + 1);       // overwrite wtab with next group
        }
        if (!PRE && f < 63) {
            __syncthreads();          // raw visible; slab[buf^1] readers done
            build_fb(buf ^ 1);
        }
        __syncthreads();              // slab[buf^1] (+ wtab) visible
        buf ^= 1;
    }

    // ---------------- epilogue: bias + LN + GELU ----------------
    const float4 sb0 = *((const float4*)(skipb_g + w8));
    const float4 sb1 = *((const float4*)(skipb_g + w8 + 4));
    const float4 bi0 = *((const float4*)(bias_g + w8));
    const float4 bi1 = *((const float4*)(bias_g + w8 + 4));
    const float4 ga0 = *((const float4*)(gamma_g + w8));
    const float4 ga1 = *((const float4*)(gamma_g + w8 + 4));
    const float4 be0 = *((const float4*)(beta_g + w8));
    const float4 be1 = *((const float4*)(beta_g + w8 + 4));
    const float add_[8] = {sb0.x + bi0.x, sb0.y + bi0.y, sb0.z + bi0.z, sb0.w + bi0.w,
                           sb1.x + bi1.x, sb1.y + bi1.y, sb1.z + bi1.z, sb1.w + bi1.w};
    const float gam[8] = {ga0.x, ga0.y, ga0.z, ga0.w, ga1.x, ga1.y, ga1.z, ga1.w};
    const float bet[8] = {be0.x, be0.y, be0.z, be0.w, be1.x, be1.y, be1.z, be1.w};
    const float cs = 1.f / (512.f * 126.f);

    float c[8];
    #pragma unroll
    for (int q = 0; q < 4; ++q) {
        c[2*q]   = acc2[q].x + (float)doti[2*q]   * cs + add_[2*q];
        c[2*q+1] = acc2[q].y + (float)doti[2*q+1] * cs + add_[2*q+1];
    }
    float s = 0.f;
    #pragma unroll
    for (int k = 0; k < 8; ++k) s += c[k];
    s += __shfl_xor(s, 1); s += __shfl_xor(s, 2); s += __shfl_xor(s, 4);
    const float mean = s * 0.015625f;
    float v = 0.f;
    #pragma unroll
    for (int k = 0; k < 8; ++k) { const float d = c[k] - mean; v += d * d; }
    v += __shfl_xor(v, 1); v += __shfl_xor(v, 2); v += __shfl_xor(v, 4);
    const float inv = rsqrtf(v * 0.015625f + 1e-5f);
    float o[8];
    #pragma unroll
    for (int k = 0; k < 8; ++k) {
        const float y = (c[k] - mean) * inv * gam[k] + bet[k];
        o[k] = 0.5f * y * (1.f + erff(y * 0.70710678118f));
    }
    float4* dst = (float4*)(out_g + (size_t)(row0 + row) * 64 + w8);
    dst[0] = make_float4(o[0], o[1], o[2], o[3]);
    dst[1] = make_float4(o[4], o[5], o[6], o[7]);
}

extern "C" void kernel_launch(void* const* d_in, const int* in_sizes, int n_in,
                              void* d_out, int out_size, void* d_ws, size_t ws_size,
                              hipStream_t stream) {
    (void)in_sizes; (void)n_in; (void)out_size;
    const bool pre = (ws_size >= (size_t)(64 * SLABB));
    if (pre) {
        kan_prep<<<64, 256, 0, stream>>>((const float*)d_in[3], (unsigned char*)d_ws);
        kan_fused<true><<<512, NTHREADS, 0, stream>>>(
            (const float*)d_in[0], (const float*)d_in[1], (const float*)d_in[2],
            (const float*)d_in[3], (const float*)d_in[4], (const float*)d_in[5],
            (const float*)d_in[6], (const float*)d_in[7], (const float*)d_in[8],
            (const float*)d_in[9], (const unsigned char*)d_ws, (float*)d_out);
    } else {
        kan_fused<false><<<512, NTHREADS, 0, stream>>>(
            (const float*)d_in[0], (const float*)d_in[1], (const float*)d_in[2],
            (const float*)d_in[3], (const float*)d_in[4], (const float*)d_in[5],
            (const float*)d_in[6], (const float*)d_in[7], (const float*)d_in[8],
            (const float*)d_in[9], (const unsigned char*)d_ws, (float*)d_out);
    }
}

// Round 7
// 41.797 us; speedup vs baseline: 1.3947x; 1.3947x over previous
//
#include <hip/hip_runtime.h>
#include <math.h>

// KAN layer fused kernel for MI355X (gfx950), round 7.
// BATCH=32768, IN_FEATURES=64, GRID=64, WIDTH=64, DEGREE=3, clamped uniform knots.
//
// r6's counted-vmcnt LDS pipeline raced (m152 lesson). r7 removes the entire
// class: the windowed-int8 table (1MB, L2-resident) is gathered DIRECTLY from
// global memory. Threads reshaped to 4 widths each (524288 threads = 8192
// waves = 32 waves/CU ceiling): per feature = 1 global_load_dwordx4 (coalesced
// 256B per 16-lane group) + 1 broadcast ds_read_b64 (wtab) + 4 v_dot4_i32_i8.
// Only 2 __syncthreads per 8-feature wtab rebuild (16 barriers total).

#define NTHREADS 512
#define ROWSB 32              // rows per block
#define WROW 256              // window row stride bytes (64 w * 4B, line-aligned)
#define SLABF 15616           // 61 * 256 bytes per feature

typedef float v2f __attribute__((ext_vector_type(2)));

#if __has_builtin(__builtin_amdgcn_sdot4)
#define SDOT4(a, b, c) __builtin_amdgcn_sdot4((int)(a), (int)(b), (c), false)
#else
__device__ __forceinline__ int sdot4_sw(unsigned a, unsigned b, int c) {
    return c + (int)(signed char)(a) * (int)(signed char)(b)
             + (int)(signed char)(a >> 8)  * (int)(signed char)(b >> 8)
             + (int)(signed char)(a >> 16) * (int)(signed char)(b >> 16)
             + (int)(signed char)(a >> 24) * (int)(signed char)(b >> 24);
}
#define SDOT4(a, b, c) sdot4_sw((a), (b), (c))
#endif

__device__ __forceinline__ unsigned int f2bf1(float f) {
    unsigned int u = __float_as_uint(f);
    return (u + 0x7fffu + ((u >> 16) & 1u)) >> 16;   // RNE bf16
}
__device__ __forceinline__ v2f up2(unsigned int u) {   // 2x bf16 -> 2x f32
    v2f r;
    r.x = __uint_as_float(u << 16);
    r.y = __uint_as_float(u & 0xffff0000u);
    return r;
}
__device__ __forceinline__ unsigned int q8(float v) {  // int8(x512) clamp, low byte
    const float s = fminf(fmaxf(v * 512.f, -127.f), 127.f);
    return (unsigned int)((int)rintf(s)) & 255u;
}

// prep: coeff f32 [64][64][64] -> windowed int8 image ws[f][g0*256 + w*4]
// dword at (f,g0,w) = 4 packed taps c[g0..g0+3][w] (x512, int8).
__global__ __launch_bounds__(256) void kan_prep(
    const float* __restrict__ coeff_g,
    unsigned char* __restrict__ ws8)
{
    __shared__ unsigned char raw[4096];     // int8 [g][w]
    const int f = blockIdx.x;               // 64
    const int t = threadIdx.x;              // 256
    {   // quantize 16 coeffs/thread
        const float* src = coeff_g + (size_t)f * 4096 + t * 16;
        const float4 a0 = ((const float4*)src)[0];
        const float4 a1 = ((const float4*)src)[1];
        const float4 a2 = ((const float4*)src)[2];
        const float4 a3 = ((const float4*)src)[3];
        uint4 p;
        p.x = q8(a0.x) | (q8(a0.y) << 8) | (q8(a0.z) << 16) | (q8(a0.w) << 24);
        p.y = q8(a1.x) | (q8(a1.y) << 8) | (q8(a1.z) << 16) | (q8(a1.w) << 24);
        p.z = q8(a2.x) | (q8(a2.y) << 8) | (q8(a2.z) << 16) | (q8(a2.w) << 24);
        p.w = q8(a3.x) | (q8(a3.y) << 8) | (q8(a3.z) << 16) | (q8(a3.w) << 24);
        ((uint4*)raw)[t] = p;
    }
    __syncthreads();
    unsigned char* dst = ws8 + (size_t)f * SLABF;
    #pragma unroll
    for (int i = 0; i < 16; ++i) {          // 61*64 = 3904 window dwords
        const int idx = i * 256 + t;
        if (idx < 3904) {
            const int g0 = idx >> 6, w = idx & 63;
            const unsigned int d = (unsigned int)raw[g0 * 64 + w]
                                 | ((unsigned int)raw[(g0 + 1) * 64 + w] << 8)
                                 | ((unsigned int)raw[(g0 + 2) * 64 + w] << 16)
                                 | ((unsigned int)raw[(g0 + 3) * 64 + w] << 24);
            *(unsigned int*)(dst + g0 * WROW + w * 4) = d;
        }
    }
}

template<bool PRE>
__global__ __launch_bounds__(NTHREADS, 8) void kan_fused(
    const float* __restrict__ x_g,      // [32768][64]
    const float* __restrict__ shift_g,  // [64]
    const float* __restrict__ lsc_g,    // [64]
    const float* __restrict__ coeff_g,  // [64][64][64] (f,g,w)
    const float* __restrict__ skipW_g,  // [64][64] (w,f)
    const float* __restrict__ skipb_g,  // [64]
    const float* __restrict__ bias_g,   // [64]
    const float* __restrict__ gamma_g,  // [64]
    const float* __restrict__ beta_g,   // [64]
    const float* __restrict__ knots_g,  // [68]
    const unsigned char* __restrict__ ws8,
    float* __restrict__ out_g)          // [32768][64]
{
    __shared__ float  xin[64][ROWSB];       // 8 KB [f][row]
    __shared__ unsigned short skw[4096];    // 8 KB bf16 [f][w]
    __shared__ uint2  wtab2[8 * ROWSB];     // 2 KB [fc][row]: {wpack, m}
    __shared__ float  knot_s[68];
    __shared__ float  scale_s[64];
    __shared__ float  shift_s[64];

    const int t = threadIdx.x;
    const int row0 = blockIdx.x * ROWSB;

    // ---------------- prologue staging ----------------
    {   // inputs: transpose to [f][row]; 4 floats/thread
        const int r = t >> 4, f0 = (t & 15) << 2;
        const float4 a = *((const float4*)(x_g + (size_t)(row0 + r) * 64 + f0));
        xin[f0 + 0][r] = a.x; xin[f0 + 1][r] = a.y;
        xin[f0 + 2][r] = a.z; xin[f0 + 3][r] = a.w;
    }
    {   // skip W: read [w][f] coalesced, write bf16 transposed [f][w]
        const int w = t >> 3, f0 = (t & 7) << 3;
        const float4* src = (const float4*)(skipW_g + (size_t)w * 64 + f0);
        const float4 a0 = src[0], a1 = src[1];
        skw[(f0 + 0) * 64 + w] = (unsigned short)f2bf1(a0.x);
        skw[(f0 + 1) * 64 + w] = (unsigned short)f2bf1(a0.y);
        skw[(f0 + 2) * 64 + w] = (unsigned short)f2bf1(a0.z);
        skw[(f0 + 3) * 64 + w] = (unsigned short)f2bf1(a0.w);
        skw[(f0 + 4) * 64 + w] = (unsigned short)f2bf1(a1.x);
        skw[(f0 + 5) * 64 + w] = (unsigned short)f2bf1(a1.y);
        skw[(f0 + 6) * 64 + w] = (unsigned short)f2bf1(a1.z);
        skw[(f0 + 7) * 64 + w] = (unsigned short)f2bf1(a1.w);
    }
    if (t < 64) {
        scale_s[t] = log1pf(__expf(lsc_g[t])) + 0.001f;   // softplus + 0.001
        shift_s[t] = shift_g[t];
    }
    if (t < 68) knot_s[t] = knots_g[t];
    __syncthreads();

    const int lane = t & 63;
    const int wave = t >> 6;          // 0..7
    const int wc   = lane & 15;       // 0..15 -> widths wc*4..+3
    const int rsub = lane >> 4;       // 0..3
    const int row  = (wave << 2) + rsub;   // 0..31
    const int w4   = wc << 2;

    // ---------------- skip pass: acc += x[row][f] * W[w][f] (bf16) ----------------
    v2f acc2[2];
    acc2[0] = (v2f){0.f, 0.f}; acc2[1] = (v2f){0.f, 0.f};
    #pragma unroll 8
    for (int f = 0; f < 64; ++f) {
        const float xv = xin[f][row];
        const uint2 sp = *((const uint2*)(&skw[(f << 6) + w4]));
        const v2f xv2 = {xv, xv};
        acc2[0] += xv2 * up2(sp.x);
        acc2[1] += xv2 * up2(sp.y);
    }

    int doti[4] = {0, 0, 0, 0};
    float facc[4] = {0.f, 0.f, 0.f, 0.f};

    // ---------------- main loop: 8 groups of 8 features ----------------
    for (int g = 0; g < 8; ++g) {
        __syncthreads();   // close previous group's wtab readers
        if (t < 256) {     // basis weights for features 8g..8g+7, rows 0..31
            const int fc_ = t >> 5, r_ = t & 31;
            const int feat = (g << 3) + fc_;
            const float xs = (xin[feat][r_] - shift_s[feat]) * scale_s[feat];
            const float xq = 1.f / (1.f + __expf(-xs));   // sigmoid in [0,1]
            int m = (int)floorf(xq * 61.f);
            m = m < 0 ? 0 : (m > 60 ? 60 : m);
            const int i = m + 3;
            float left[4], right[4], N[4];
            N[0] = 1.f;
            #pragma unroll
            for (int j = 1; j <= 3; ++j) {
                left[j]  = xq - knot_s[i + 1 - j];
                right[j] = knot_s[i + j] - xq;
                float saved = 0.f;
                #pragma unroll
                for (int rr = 0; rr < j; ++rr) {
                    const float temp = N[rr] * __builtin_amdgcn_rcpf(right[rr + 1] + left[j - rr]);
                    N[rr] = saved + right[rr + 1] * temp;
                    saved = left[j - rr] * temp;
                }
                N[j] = saved;
            }
            const unsigned int q0 = (unsigned int)(int)(fmaxf(N[0], 0.f) * 126.f + 0.5f);
            const unsigned int q1 = (unsigned int)(int)(fmaxf(N[1], 0.f) * 126.f + 0.5f);
            const unsigned int q2 = (unsigned int)(int)(fmaxf(N[2], 0.f) * 126.f + 0.5f);
            const unsigned int q3 = (unsigned int)(int)(fmaxf(N[3], 0.f) * 126.f + 0.5f);
            wtab2[t] = make_uint2(q0 | (q1 << 8) | (q2 << 16) | (q3 << 24),
                                  (unsigned int)m);
        }
        __syncthreads();   // publish wtab group g

        if (PRE) {
            #pragma unroll 2
            for (int fc = 0; fc < 8; ++fc) {
                const int f = (g << 3) + fc;
                const uint2 wv = wtab2[(fc << 5) + row];     // broadcast x16 lanes
                const uint4 A = *((const uint4*)(ws8 + (size_t)f * SLABF
                                                 + (wv.y << 8) + (wc << 4)));
                doti[0] = SDOT4(wv.x, A.x, doti[0]);
                doti[1] = SDOT4(wv.x, A.y, doti[1]);
                doti[2] = SDOT4(wv.x, A.z, doti[2]);
                doti[3] = SDOT4(wv.x, A.w, doti[3]);
            }
        } else {
            #pragma unroll 2
            for (int fc = 0; fc < 8; ++fc) {
                const int f = (g << 3) + fc;
                const uint2 wv = wtab2[(fc << 5) + row];
                const float* cb = coeff_g + ((size_t)f << 12) + (wv.y << 6) + w4;
                const float4 c0 = *((const float4*)cb);
                const float4 c1 = *((const float4*)(cb + 64));
                const float4 c2 = *((const float4*)(cb + 128));
                const float4 c3 = *((const float4*)(cb + 192));
                const float q0 = (float)(wv.x & 255u);
                const float q1 = (float)((wv.x >> 8) & 255u);
                const float q2 = (float)((wv.x >> 16) & 255u);
                const float q3 = (float)((wv.x >> 24) & 255u);
                facc[0] += q0 * c0.x + q1 * c1.x + q2 * c2.x + q3 * c3.x;
                facc[1] += q0 * c0.y + q1 * c1.y + q2 * c2.y + q3 * c3.y;
                facc[2] += q0 * c0.z + q1 * c1.z + q2 * c2.z + q3 * c3.z;
                facc[3] += q0 * c0.w + q1 * c1.w + q2 * c2.w + q3 * c3.w;
            }
        }
    }

    // ---------------- epilogue: bias + LN + GELU ----------------
    const float4 sb = *((const float4*)(skipb_g + w4));
    const float4 bi = *((const float4*)(bias_g + w4));
    const float4 ga = *((const float4*)(gamma_g + w4));
    const float4 be = *((const float4*)(beta_g + w4));
    const float add_[4] = {sb.x + bi.x, sb.y + bi.y, sb.z + bi.z, sb.w + bi.w};
    const float gam[4] = {ga.x, ga.y, ga.z, ga.w};
    const float bet[4] = {be.x, be.y, be.z, be.w};
    const float cs = PRE ? (1.f / (512.f * 126.f)) : (1.f / 126.f);

    float c[4];
    #pragma unroll
    for (int k = 0; k < 4; ++k) {
        const float sp = PRE ? (float)doti[k] * cs : facc[k] * cs;
        c[k] = acc2[k >> 1][k & 1] + sp + add_[k];
    }
    float s = c[0] + c[1] + c[2] + c[3];
    s += __shfl_xor(s, 1); s += __shfl_xor(s, 2);
    s += __shfl_xor(s, 4); s += __shfl_xor(s, 8);
    const float mean = s * 0.015625f;
    float v = 0.f;
    #pragma unroll
    for (int k = 0; k < 4; ++k) { const float d = c[k] - mean; v += d * d; }
    v += __shfl_xor(v, 1); v += __shfl_xor(v, 2);
    v += __shfl_xor(v, 4); v += __shfl_xor(v, 8);
    const float inv = rsqrtf(v * 0.015625f + 1e-5f);
    float o[4];
    #pragma unroll
    for (int k = 0; k < 4; ++k) {
        const float y = (c[k] - mean) * inv * gam[k] + bet[k];
        o[k] = 0.5f * y * (1.f + erff(y * 0.70710678118f));
    }
    *((float4*)(out_g + (size_t)(row0 + row) * 64 + w4)) =
        make_float4(o[0], o[1], o[2], o[3]);
}

extern "C" void kernel_launch(void* const* d_in, const int* in_sizes, int n_in,
                              void* d_out, int out_size, void* d_ws, size_t ws_size,
                              hipStream_t stream) {
    (void)in_sizes; (void)n_in; (void)out_size;
    const bool pre = (ws_size >= (size_t)(64 * SLABF));
    if (pre) {
        kan_prep<<<64, 256, 0, stream>>>((const float*)d_in[3], (unsigned char*)d_ws);
        kan_fused<true><<<1024, NTHREADS, 0, stream>>>(
            (const float*)d_in[0], (const float*)d_in[1], (const float*)d_in[2],
            (const float*)d_in[3], (const float*)d_in[4], (const float*)d_in[5],
            (const float*)d_in[6], (const float*)d_in[7], (const float*)d_in[8],
            (const float*)d_in[9], (const unsigned char*)d_ws, (float*)d_out);
    } else {
        kan_fused<false><<<1024, NTHREADS, 0, stream>>>(
            (const float*)d_in[0], (const float*)d_in[1], (const float*)d_in[2],
            (const float*)d_in[3], (const float*)d_in[4], (const float*)d_in[5],
            (const float*)d_in[6], (const float*)d_in[7], (const float*)d_in[8],
            (const float*)d_in[9], (const unsigned char*)d_ws, (float*)d_out);
    }
}

// Round 8
// 41.559 us; speedup vs baseline: 1.4027x; 1.0057x over previous
//
#include <hip/hip_runtime.h>
#include <math.h>

// KAN layer fused kernel for MI355X (gfx950), round 8.
// BATCH=32768, IN_FEATURES=64, GRID=64, WIDTH=64, DEGREE=3, clamped uniform knots.
//
// r7 (L2-direct windowed-int8 gather, 41.8us) was latency-bound: ~1-2 gathers in
// flight per thread. r8: 4-deep batched gather (4x ds_read_b64 wtab -> 4x
// independent global_load_dwordx4 -> 16 sdot4), slab stride padded to 16KB so
// addressing is shift-only, launch_bounds(512,6) for VGPR headroom (no spill),
// prep widened to 976 blocks (one window dword/thread, no LDS).

#define NTHREADS 512
#define ROWSB 32              // rows per block
#define SLABF 16384           // padded per-feature window slab stride (bytes)

typedef float v2f __attribute__((ext_vector_type(2)));

#if __has_builtin(__builtin_amdgcn_sdot4)
#define SDOT4(a, b, c) __builtin_amdgcn_sdot4((int)(a), (int)(b), (c), false)
#else
__device__ __forceinline__ int sdot4_sw(unsigned a, unsigned b, int c) {
    return c + (int)(signed char)(a) * (int)(signed char)(b)
             + (int)(signed char)(a >> 8)  * (int)(signed char)(b >> 8)
             + (int)(signed char)(a >> 16) * (int)(signed char)(b >> 16)
             + (int)(signed char)(a >> 24) * (int)(signed char)(b >> 24);
}
#define SDOT4(a, b, c) sdot4_sw((a), (b), (c))
#endif

__device__ __forceinline__ unsigned int f2bf1(float f) {
    unsigned int u = __float_as_uint(f);
    return (u + 0x7fffu + ((u >> 16) & 1u)) >> 16;   // RNE bf16
}
__device__ __forceinline__ v2f up2(unsigned int u) {   // 2x bf16 -> 2x f32
    v2f r;
    r.x = __uint_as_float(u << 16);
    r.y = __uint_as_float(u & 0xffff0000u);
    return r;
}
__device__ __forceinline__ unsigned int q8(float v) {  // int8(x512) clamp, low byte
    const float s = fminf(fmaxf(v * 512.f, -127.f), 127.f);
    return (unsigned int)((int)rintf(s)) & 255u;
}

// prep: one window dword per thread. ws[f*16384 + g0*256 + w*4] =
// packed int8 taps {c[f][g0..g0+3][w] * 512}. 976 blocks x 256 = 249856 dwords.
__global__ __launch_bounds__(256) void kan_prep(
    const float* __restrict__ coeff_g,
    unsigned char* __restrict__ ws8)
{
    const int idx = blockIdx.x * 256 + threadIdx.x;   // < 64*61*64 = 249856
    const int f = idx / 3904;
    const int rem = idx - f * 3904;
    const int g0 = rem >> 6, w = rem & 63;
    const float* src = coeff_g + ((size_t)f << 12) + (g0 << 6) + w;
    const unsigned int d = q8(src[0])
                         | (q8(src[64])  << 8)
                         | (q8(src[128]) << 16)
                         | (q8(src[192]) << 24);
    *(unsigned int*)(ws8 + ((size_t)f << 14) + (g0 << 8) + (w << 2)) = d;
}

template<bool PRE>
__global__ __launch_bounds__(NTHREADS, 6) void kan_fused(
    const float* __restrict__ x_g,      // [32768][64]
    const float* __restrict__ shift_g,  // [64]
    const float* __restrict__ lsc_g,    // [64]
    const float* __restrict__ coeff_g,  // [64][64][64] (f,g,w)
    const float* __restrict__ skipW_g,  // [64][64] (w,f)
    const float* __restrict__ skipb_g,  // [64]
    const float* __restrict__ bias_g,   // [64]
    const float* __restrict__ gamma_g,  // [64]
    const float* __restrict__ beta_g,   // [64]
    const float* __restrict__ knots_g,  // [68]
    const unsigned char* __restrict__ ws8,
    float* __restrict__ out_g)          // [32768][64]
{
    __shared__ float  xin[64][ROWSB];       // 8 KB [f][row]
    __shared__ unsigned short skw[4096];    // 8 KB bf16 [f][w]
    __shared__ uint2  wtab2[8 * ROWSB];     // 2 KB [fc][row]: {wpack, m<<8}
    __shared__ float  knot_s[68];
    __shared__ float  scale_s[64];
    __shared__ float  shift_s[64];

    const int t = threadIdx.x;
    const int row0 = blockIdx.x * ROWSB;

    // ---------------- prologue staging ----------------
    {   // inputs: transpose to [f][row]; 4 floats/thread
        const int r = t >> 4, f0 = (t & 15) << 2;
        const float4 a = *((const float4*)(x_g + (size_t)(row0 + r) * 64 + f0));
        xin[f0 + 0][r] = a.x; xin[f0 + 1][r] = a.y;
        xin[f0 + 2][r] = a.z; xin[f0 + 3][r] = a.w;
    }
    {   // skip W: read [w][f] coalesced, write bf16 transposed [f][w]
        const int w = t >> 3, f0 = (t & 7) << 3;
        const float4* src = (const float4*)(skipW_g + (size_t)w * 64 + f0);
        const float4 a0 = src[0], a1 = src[1];
        skw[(f0 + 0) * 64 + w] = (unsigned short)f2bf1(a0.x);
        skw[(f0 + 1) * 64 + w] = (unsigned short)f2bf1(a0.y);
        skw[(f0 + 2) * 64 + w] = (unsigned short)f2bf1(a0.z);
        skw[(f0 + 3) * 64 + w] = (unsigned short)f2bf1(a0.w);
        skw[(f0 + 4) * 64 + w] = (unsigned short)f2bf1(a1.x);
        skw[(f0 + 5) * 64 + w] = (unsigned short)f2bf1(a1.y);
        skw[(f0 + 6) * 64 + w] = (unsigned short)f2bf1(a1.z);
        skw[(f0 + 7) * 64 + w] = (unsigned short)f2bf1(a1.w);
    }
    if (t < 64) {
        scale_s[t] = log1pf(__expf(lsc_g[t])) + 0.001f;   // softplus + 0.001
        shift_s[t] = shift_g[t];
    }
    if (t < 68) knot_s[t] = knots_g[t];
    __syncthreads();

    const int lane = t & 63;
    const int wave = t >> 6;          // 0..7
    const int wc   = lane & 15;       // 0..15 -> widths wc*4..+3
    const int rsub = lane >> 4;       // 0..3
    const int row  = (wave << 2) + rsub;   // 0..31
    const int w4   = wc << 2;

    // ---------------- skip pass: acc += x[row][f] * W[w][f] (bf16) ----------------
    v2f acc2[2];
    acc2[0] = (v2f){0.f, 0.f}; acc2[1] = (v2f){0.f, 0.f};
    #pragma unroll 8
    for (int f = 0; f < 64; ++f) {
        const float xv = xin[f][row];
        const uint2 sp = *((const uint2*)(&skw[(f << 6) + w4]));
        const v2f xv2 = {xv, xv};
        acc2[0] += xv2 * up2(sp.x);
        acc2[1] += xv2 * up2(sp.y);
    }

    int doti[4] = {0, 0, 0, 0};
    float facc[4] = {0.f, 0.f, 0.f, 0.f};
    const unsigned char* const wbase = ws8 + (wc << 4);

    // ---------------- main loop: 8 groups of 8 features ----------------
    for (int g = 0; g < 8; ++g) {
        __syncthreads();   // close previous group's wtab readers
        if (t < 256) {     // basis weights for features 8g..8g+7, rows 0..31
            const int fc_ = t >> 5, r_ = t & 31;
            const int feat = (g << 3) + fc_;
            const float xs = (xin[feat][r_] - shift_s[feat]) * scale_s[feat];
            const float xq = 1.f / (1.f + __expf(-xs));   // sigmoid in [0,1]
            int m = (int)floorf(xq * 61.f);
            m = m < 0 ? 0 : (m > 60 ? 60 : m);
            const int i = m + 3;
            float left[4], right[4], N[4];
            N[0] = 1.f;
            #pragma unroll
            for (int j = 1; j <= 3; ++j) {
                left[j]  = xq - knot_s[i + 1 - j];
                right[j] = knot_s[i + j] - xq;
                float saved = 0.f;
                #pragma unroll
                for (int rr = 0; rr < j; ++rr) {
                    const float temp = N[rr] * __builtin_amdgcn_rcpf(right[rr + 1] + left[j - rr]);
                    N[rr] = saved + right[rr + 1] * temp;
                    saved = left[j - rr] * temp;
                }
                N[j] = saved;
            }
            const unsigned int q0 = (unsigned int)(int)(fmaxf(N[0], 0.f) * 126.f + 0.5f);
            const unsigned int q1 = (unsigned int)(int)(fmaxf(N[1], 0.f) * 126.f + 0.5f);
            const unsigned int q2 = (unsigned int)(int)(fmaxf(N[2], 0.f) * 126.f + 0.5f);
            const unsigned int q3 = (unsigned int)(int)(fmaxf(N[3], 0.f) * 126.f + 0.5f);
            wtab2[t] = make_uint2(q0 | (q1 << 8) | (q2 << 16) | (q3 << 24),
                                  (unsigned int)(m << 8));
        }
        __syncthreads();   // publish wtab group g

        if (PRE) {
            const unsigned char* const gbase = wbase + ((size_t)g << 17);  // g*8*SLABF
            #pragma unroll
            for (int h = 0; h < 2; ++h) {
                // 4 wtab reads, then 4 independent gathers, then 16 sdot4
                const uint2 wv0 = wtab2[(((h << 2) + 0) << 5) + row];
                const uint2 wv1 = wtab2[(((h << 2) + 1) << 5) + row];
                const uint2 wv2 = wtab2[(((h << 2) + 2) << 5) + row];
                const uint2 wv3 = wtab2[(((h << 2) + 3) << 5) + row];
                const uint4 A0 = *((const uint4*)(gbase + (((h << 2) + 0) << 14) + wv0.y));
                const uint4 A1 = *((const uint4*)(gbase + (((h << 2) + 1) << 14) + wv1.y));
                const uint4 A2 = *((const uint4*)(gbase + (((h << 2) + 2) << 14) + wv2.y));
                const uint4 A3 = *((const uint4*)(gbase + (((h << 2) + 3) << 14) + wv3.y));
                doti[0] = SDOT4(wv0.x, A0.x, doti[0]);
                doti[1] = SDOT4(wv0.x, A0.y, doti[1]);
                doti[2] = SDOT4(wv0.x, A0.z, doti[2]);
                doti[3] = SDOT4(wv0.x, A0.w, doti[3]);
                doti[0] = SDOT4(wv1.x, A1.x, doti[0]);
                doti[1] = SDOT4(wv1.x, A1.y, doti[1]);
                doti[2] = SDOT4(wv1.x, A1.z, doti[2]);
                doti[3] = SDOT4(wv1.x, A1.w, doti[3]);
                doti[0] = SDOT4(wv2.x, A2.x, doti[0]);
                doti[1] = SDOT4(wv2.x, A2.y, doti[1]);
                doti[2] = SDOT4(wv2.x, A2.z, doti[2]);
                doti[3] = SDOT4(wv2.x, A2.w, doti[3]);
                doti[0] = SDOT4(wv3.x, A3.x, doti[0]);
                doti[1] = SDOT4(wv3.x, A3.y, doti[1]);
                doti[2] = SDOT4(wv3.x, A3.z, doti[2]);
                doti[3] = SDOT4(wv3.x, A3.w, doti[3]);
            }
        } else {
            #pragma unroll 2
            for (int fc = 0; fc < 8; ++fc) {
                const int f = (g << 3) + fc;
                const uint2 wv = wtab2[(fc << 5) + row];
                const float* cb = coeff_g + ((size_t)f << 12) + (wv.y >> 2) + w4;
                const float4 c0 = *((const float4*)cb);
                const float4 c1 = *((const float4*)(cb + 64));
                const float4 c2 = *((const float4*)(cb + 128));
                const float4 c3 = *((const float4*)(cb + 192));
                const float q0 = (float)(wv.x & 255u);
                const float q1 = (float)((wv.x >> 8) & 255u);
                const float q2 = (float)((wv.x >> 16) & 255u);
                const float q3 = (float)((wv.x >> 24) & 255u);
                facc[0] += q0 * c0.x + q1 * c1.x + q2 * c2.x + q3 * c3.x;
                facc[1] += q0 * c0.y + q1 * c1.y + q2 * c2.y + q3 * c3.y;
                facc[2] += q0 * c0.z + q1 * c1.z + q2 * c2.z + q3 * c3.z;
                facc[3] += q0 * c0.w + q1 * c1.w + q2 * c2.w + q3 * c3.w;
            }
        }
    }

    // ---------------- epilogue: bias + LN + GELU ----------------
    const float4 sb = *((const float4*)(skipb_g + w4));
    const float4 bi = *((const float4*)(bias_g + w4));
    const float4 ga = *((const float4*)(gamma_g + w4));
    const float4 be = *((const float4*)(beta_g + w4));
    const float add_[4] = {sb.x + bi.x, sb.y + bi.y, sb.z + bi.z, sb.w + bi.w};
    const float gam[4] = {ga.x, ga.y, ga.z, ga.w};
    const float bet[4] = {be.x, be.y, be.z, be.w};
    const float cs = PRE ? (1.f / (512.f * 126.f)) : (1.f / 126.f);

    float c[4];
    #pragma unroll
    for (int k = 0; k < 4; ++k) {
        const float sp = PRE ? (float)doti[k] * cs : facc[k] * cs;
        c[k] = acc2[k >> 1][k & 1] + sp + add_[k];
    }
    float s = c[0] + c[1] + c[2] + c[3];
    s += __shfl_xor(s, 1); s += __shfl_xor(s, 2);
    s += __shfl_xor(s, 4); s += __shfl_xor(s, 8);
    const float mean = s * 0.015625f;
    float v = 0.f;
    #pragma unroll
    for (int k = 0; k < 4; ++k) { const float d = c[k] - mean; v += d * d; }
    v += __shfl_xor(v, 1); v += __shfl_xor(v, 2);
    v += __shfl_xor(v, 4); v += __shfl_xor(v, 8);
    const float inv = rsqrtf(v * 0.015625f + 1e-5f);
    float o[4];
    #pragma unroll
    for (int k = 0; k < 4; ++k) {
        const float y = (c[k] - mean) * inv * gam[k] + bet[k];
        o[k] = 0.5f * y * (1.f + erff(y * 0.70710678118f));
    }
    *((float4*)(out_g + (size_t)(row0 + row) * 64 + w4)) =
        make_float4(o[0], o[1], o[2], o[3]);
}

extern "C" void kernel_launch(void* const* d_in, const int* in_sizes, int n_in,
                              void* d_out, int out_size, void* d_ws, size_t ws_size,
                              hipStream_t stream) {
    (void)in_sizes; (void)n_in; (void)out_size;
    const bool pre = (ws_size >= (size_t)(64 * SLABF));
    if (pre) {
        kan_prep<<<976, 256, 0, stream>>>((const float*)d_in[3], (unsigned char*)d_ws);
        kan_fused<true><<<1024, NTHREADS, 0, stream>>>(
            (const float*)d_in[0], (const float*)d_in[1], (const float*)d_in[2],
            (const float*)d_in[3], (const float*)d_in[4], (const float*)d_in[5],
            (const float*)d_in[6], (const float*)d_in[7], (const float*)d_in[8],
            (const float*)d_in[9], (const unsigned char*)d_ws, (float*)d_out);
    } else {
        kan_fused<false><<<1024, NTHREADS, 0, stream>>>(
            (const float*)d_in[0], (const float*)d_in[1], (const float*)d_in[2],
            (const float*)d_in[3], (const float*)d_in[4], (const float*)d_in[5],
            (const float*)d_in[6], (const float*)d_in[7], (const float*)d_in[8],
            (const float*)d_in[9], (const unsigned char*)d_ws, (float*)d_out);
    }
}

// Round 9
// 35.136 us; speedup vs baseline: 1.6591x; 1.1828x over previous
//
#include <hip/hip_runtime.h>
#include <math.h>

// KAN layer fused kernel for MI355X (gfx950), round 9.
// BATCH=32768, IN_FEATURES=64, GRID=64, WIDTH=64, DEGREE=3, clamped uniform knots.
//
// vs r8: (1) skip-GEMM moved to MFMA (2x mfma_f32_16x16x32_bf16 per wave;
// A=x[32x64] bf16, B=W^T; fragments from XOR-swizzled LDS; result bounced via
// 8KB LDS tile back to the gather thread layout) -- removes ~500 VALU
// instr/thread; (2) basis rebuilt per 16 features (512 entries = 1/thread,
// barriers 16 -> 8). Windowed-int8 L2-direct gather unchanged (proven r7/r8).

#define NTHREADS 512
#define ROWSB 32              // rows per block
#define SLABF 16384           // padded per-feature window slab stride (bytes)

typedef float v2f  __attribute__((ext_vector_type(2)));
typedef short bf16x8 __attribute__((ext_vector_type(8)));
typedef float f32x4  __attribute__((ext_vector_type(4)));

#if __has_builtin(__builtin_amdgcn_sdot4)
#define SDOT4(a, b, c) __builtin_amdgcn_sdot4((int)(a), (int)(b), (c), false)
#else
__device__ __forceinline__ int sdot4_sw(unsigned a, unsigned b, int c) {
    return c + (int)(signed char)(a) * (int)(signed char)(b)
             + (int)(signed char)(a >> 8)  * (int)(signed char)(b >> 8)
             + (int)(signed char)(a >> 16) * (int)(signed char)(b >> 16)
             + (int)(signed char)(a >> 24) * (int)(signed char)(b >> 24);
}
#define SDOT4(a, b, c) sdot4_sw((a), (b), (c))
#endif

__device__ __forceinline__ unsigned int f2bf1(float f) {
    unsigned int u = __float_as_uint(f);
    return (u + 0x7fffu + ((u >> 16) & 1u)) >> 16;   // RNE bf16
}
__device__ __forceinline__ unsigned int q8(float v) {  // int8(x512) clamp, low byte
    const float s = fminf(fmaxf(v * 512.f, -127.f), 127.f);
    return (unsigned int)((int)rintf(s)) & 255u;
}

// prep: one window dword per thread. ws[f*16384 + g0*256 + w*4] =
// packed int8 taps {c[f][g0..g0+3][w] * 512}. 976 blocks x 256 = 249856 dwords.
__global__ __launch_bounds__(256) void kan_prep(
    const float* __restrict__ coeff_g,
    unsigned char* __restrict__ ws8)
{
    const int idx = blockIdx.x * 256 + threadIdx.x;   // < 64*61*64 = 249856
    const int f = idx / 3904;
    const int rem = idx - f * 3904;
    const int g0 = rem >> 6, w = rem & 63;
    const float* src = coeff_g + ((size_t)f << 12) + (g0 << 6) + w;
    const unsigned int d = q8(src[0])
                         | (q8(src[64])  << 8)
                         | (q8(src[128]) << 16)
                         | (q8(src[192]) << 24);
    *(unsigned int*)(ws8 + ((size_t)f << 14) + (g0 << 8) + (w << 2)) = d;
}

template<bool PRE>
__global__ __launch_bounds__(NTHREADS, 6) void kan_fused(
    const float* __restrict__ x_g,      // [32768][64]
    const float* __restrict__ shift_g,  // [64]
    const float* __restrict__ lsc_g,    // [64]
    const float* __restrict__ coeff_g,  // [64][64][64] (f,g,w)
    const float* __restrict__ skipW_g,  // [64][64] (w,f)
    const float* __restrict__ skipb_g,  // [64]
    const float* __restrict__ bias_g,   // [64]
    const float* __restrict__ gamma_g,  // [64]
    const float* __restrict__ beta_g,   // [64]
    const float* __restrict__ knots_g,  // [68]
    const unsigned char* __restrict__ ws8,
    float* __restrict__ out_g)          // [32768][64]
{
    __shared__ float  xin[64][ROWSB];        // 8 KB [f][row] f32 (basis input)
    __shared__ unsigned short xb[32 * 64];   // 4 KB bf16 [row][f], XOR-swizzled
    __shared__ unsigned short wst[64 * 64];  // 8 KB bf16 [w][f], XOR-swizzled
    __shared__ float  skps[32][64];          // 8 KB skip GEMM result [row][w]
    __shared__ uint2  wtab2[16 * 32];        // 4 KB [fc][row]: {wpack, m<<8}
    __shared__ float  knot_s[68];
    __shared__ float  scale_s[64];
    __shared__ float  shift_s[64];

    const int t = threadIdx.x;
    const int row0 = blockIdx.x * ROWSB;

    // ---------------- prologue staging ----------------
    {   // x: f32 transpose to xin[f][row] + bf16 swizzled xb[row][f]
        const int r = t >> 4, f0 = (t & 15) << 2;
        const float4 a = *((const float4*)(x_g + (size_t)(row0 + r) * 64 + f0));
        xin[f0 + 0][r] = a.x; xin[f0 + 1][r] = a.y;
        xin[f0 + 2][r] = a.z; xin[f0 + 3][r] = a.w;
        uint2 p;
        p.x = f2bf1(a.x) | (f2bf1(a.y) << 16);
        p.y = f2bf1(a.z) | (f2bf1(a.w) << 16);
        const int byte = r * 128 + ((((t & 15) << 3)) ^ ((r & 7) << 4));
        *(uint2*)((char*)xb + byte) = p;
    }
    {   // skip W: native [w][f] layout -> bf16 swizzled wst[w][f] (no transpose!)
        const int w = t >> 3, f0 = (t & 7) << 3;
        const float4* src = (const float4*)(skipW_g + (size_t)w * 64 + f0);
        const float4 a0 = src[0], a1 = src[1];
        uint4 p;
        p.x = f2bf1(a0.x) | (f2bf1(a0.y) << 16);
        p.y = f2bf1(a0.z) | (f2bf1(a0.w) << 16);
        p.z = f2bf1(a1.x) | (f2bf1(a1.y) << 16);
        p.w = f2bf1(a1.z) | (f2bf1(a1.w) << 16);
        const int byte = w * 128 + ((((t & 7) << 4)) ^ ((w & 7) << 4));
        *(uint4*)((char*)wst + byte) = p;
    }
    if (t < 64) {
        scale_s[t] = log1pf(__expf(lsc_g[t])) + 0.001f;   // softplus + 0.001
        shift_s[t] = shift_g[t];
    }
    if (t < 68) knot_s[t] = knots_g[t];
    __syncthreads();

    const int lane = t & 63;
    const int wave = t >> 6;          // 0..7

    // ---------------- skip GEMM on matrix pipe ----------------
    // D[row][w] = x[32x64] * W^T[64x64]; wave (mtile=wave>>2, ntile=wave&3)
    // owns a 16x16 tile. A-frag: lane holds A[lane&15][(lane>>4)*8+e];
    // B-frag: B[(lane>>4)*8+e][lane&15]; D: col=lane&15, row=(lane>>4)*4+reg.
    {
        const int mtile = wave >> 2;
        const int ntile = wave & 3;
        const int arow = mtile * 16 + (lane & 15);   // sample row
        const int bcol = ntile * 16 + (lane & 15);   // width
        const int koff = (lane >> 4) << 4;           // k-slice byte offset
        f32x4 acc = {0.f, 0.f, 0.f, 0.f};
        #pragma unroll
        for (int kb = 0; kb < 2; ++kb) {
            const int kbyte = (kb << 6) + koff;
            const bf16x8 af = *(const bf16x8*)((const char*)xb
                                + arow * 128 + (kbyte ^ ((arow & 7) << 4)));
            const bf16x8 bfr = *(const bf16x8*)((const char*)wst
                                + bcol * 128 + (kbyte ^ ((bcol & 7) << 4)));
            acc = __builtin_amdgcn_mfma_f32_16x16x32_bf16(af, bfr, acc, 0, 0, 0);
        }
        #pragma unroll
        for (int rr = 0; rr < 4; ++rr)
            skps[mtile * 16 + ((lane >> 4) << 2) + rr][bcol] = acc[rr];
    }

    const int wc   = lane & 15;       // 0..15 -> widths wc*4..+3
    const int rsub = lane >> 4;       // 0..3
    const int row  = (wave << 2) + rsub;   // 0..31
    const int w4   = wc << 2;

    int doti[4] = {0, 0, 0, 0};
    float facc[4] = {0.f, 0.f, 0.f, 0.f};
    const unsigned char* const wbase = ws8 + (wc << 4);

    // ---------------- main loop: 4 groups of 16 features ----------------
    for (int g = 0; g < 4; ++g) {
        __syncthreads();   // close previous group's wtab readers (and skps writes, g=0)
        {   // basis weights for features 16g..16g+15, rows 0..31 — 1 per thread
            const int fc_ = t >> 5, r_ = t & 31;
            const int feat = (g << 4) + fc_;
            const float xs = (xin[feat][r_] - shift_s[feat]) * scale_s[feat];
            const float xq = 1.f / (1.f + __expf(-xs));   // sigmoid in [0,1]
            int m = (int)floorf(xq * 61.f);
            m = m < 0 ? 0 : (m > 60 ? 60 : m);
            const int i = m + 3;
            float left[4], right[4], N[4];
            N[0] = 1.f;
            #pragma unroll
            for (int j = 1; j <= 3; ++j) {
                left[j]  = xq - knot_s[i + 1 - j];
                right[j] = knot_s[i + j] - xq;
                float saved = 0.f;
                #pragma unroll
                for (int rr = 0; rr < j; ++rr) {
                    const float temp = N[rr] * __builtin_amdgcn_rcpf(right[rr + 1] + left[j - rr]);
                    N[rr] = saved + right[rr + 1] * temp;
                    saved = left[j - rr] * temp;
                }
                N[j] = saved;
            }
            const unsigned int q0 = (unsigned int)(int)(fmaxf(N[0], 0.f) * 126.f + 0.5f);
            const unsigned int q1 = (unsigned int)(int)(fmaxf(N[1], 0.f) * 126.f + 0.5f);
            const unsigned int q2 = (unsigned int)(int)(fmaxf(N[2], 0.f) * 126.f + 0.5f);
            const unsigned int q3 = (unsigned int)(int)(fmaxf(N[3], 0.f) * 126.f + 0.5f);
            wtab2[t] = make_uint2(q0 | (q1 << 8) | (q2 << 16) | (q3 << 24),
                                  (unsigned int)(m << 8));
        }
        __syncthreads();   // publish wtab group g

        if (PRE) {
            const unsigned char* const gbase = wbase + ((size_t)g << 18);  // g*16*SLABF
            #pragma unroll
            for (int h = 0; h < 4; ++h) {
                const uint2 wv0 = wtab2[(((h << 2) + 0) << 5) + row];
                const uint2 wv1 = wtab2[(((h << 2) + 1) << 5) + row];
                const uint2 wv2 = wtab2[(((h << 2) + 2) << 5) + row];
                const uint2 wv3 = wtab2[(((h << 2) + 3) << 5) + row];
                const uint4 A0 = *((const uint4*)(gbase + (((h << 2) + 0) << 14) + wv0.y));
                const uint4 A1 = *((const uint4*)(gbase + (((h << 2) + 1) << 14) + wv1.y));
                const uint4 A2 = *((const uint4*)(gbase + (((h << 2) + 2) << 14) + wv2.y));
                const uint4 A3 = *((const uint4*)(gbase + (((h << 2) + 3) << 14) + wv3.y));
                doti[0] = SDOT4(wv0.x, A0.x, doti[0]);
                doti[1] = SDOT4(wv0.x, A0.y, doti[1]);
                doti[2] = SDOT4(wv0.x, A0.z, doti[2]);
                doti[3] = SDOT4(wv0.x, A0.w, doti[3]);
                doti[0] = SDOT4(wv1.x, A1.x, doti[0]);
                doti[1] = SDOT4(wv1.x, A1.y, doti[1]);
                doti[2] = SDOT4(wv1.x, A1.z, doti[2]);
                doti[3] = SDOT4(wv1.x, A1.w, doti[3]);
                doti[0] = SDOT4(wv2.x, A2.x, doti[0]);
                doti[1] = SDOT4(wv2.x, A2.y, doti[1]);
                doti[2] = SDOT4(wv2.x, A2.z, doti[2]);
                doti[3] = SDOT4(wv2.x, A2.w, doti[3]);
                doti[0] = SDOT4(wv3.x, A3.x, doti[0]);
                doti[1] = SDOT4(wv3.x, A3.y, doti[1]);
                doti[2] = SDOT4(wv3.x, A3.z, doti[2]);
                doti[3] = SDOT4(wv3.x, A3.w, doti[3]);
            }
        } else {
            #pragma unroll 2
            for (int fc = 0; fc < 16; ++fc) {
                const int f = (g << 4) + fc;
                const uint2 wv = wtab2[(fc << 5) + row];
                const float* cb = coeff_g + ((size_t)f << 12) + (wv.y >> 2) + w4;
                const float4 c0 = *((const float4*)cb);
                const float4 c1 = *((const float4*)(cb + 64));
                const float4 c2 = *((const float4*)(cb + 128));
                const float4 c3 = *((const float4*)(cb + 192));
                const float q0 = (float)(wv.x & 255u);
                const float q1 = (float)((wv.x >> 8) & 255u);
                const float q2 = (float)((wv.x >> 16) & 255u);
                const float q3 = (float)((wv.x >> 24) & 255u);
                facc[0] += q0 * c0.x + q1 * c1.x + q2 * c2.x + q3 * c3.x;
                facc[1] += q0 * c0.y + q1 * c1.y + q2 * c2.y + q3 * c3.y;
                facc[2] += q0 * c0.z + q1 * c1.z + q2 * c2.z + q3 * c3.z;
                facc[3] += q0 * c0.w + q1 * c1.w + q2 * c2.w + q3 * c3.w;
            }
        }
    }

    // ---------------- epilogue: skip + bias + LN + GELU ----------------
    const float4 sk = *((const float4*)(&skps[row][w4]));
    const float4 sb = *((const float4*)(skipb_g + w4));
    const float4 bi = *((const float4*)(bias_g + w4));
    const float4 ga = *((const float4*)(gamma_g + w4));
    const float4 be = *((const float4*)(beta_g + w4));
    const float add_[4] = {sk.x + sb.x + bi.x, sk.y + sb.y + bi.y,
                           sk.z + sb.z + bi.z, sk.w + sb.w + bi.w};
    const float gam[4] = {ga.x, ga.y, ga.z, ga.w};
    const float bet[4] = {be.x, be.y, be.z, be.w};
    const float cs = PRE ? (1.f / (512.f * 126.f)) : (1.f / 126.f);

    float c[4];
    #pragma unroll
    for (int k = 0; k < 4; ++k) {
        const float sp = PRE ? (float)doti[k] * cs : facc[k] * cs;
        c[k] = sp + add_[k];
    }
    float s = c[0] + c[1] + c[2] + c[3];
    s += __shfl_xor(s, 1); s += __shfl_xor(s, 2);
    s += __shfl_xor(s, 4); s += __shfl_xor(s, 8);
    const float mean = s * 0.015625f;
    float v = 0.f;
    #pragma unroll
    for (int k = 0; k < 4; ++k) { const float d = c[k] - mean; v += d * d; }
    v += __shfl_xor(v, 1); v += __shfl_xor(v, 2);
    v += __shfl_xor(v, 4); v += __shfl_xor(v, 8);
    const float inv = rsqrtf(v * 0.015625f + 1e-5f);
    float o[4];
    #pragma unroll
    for (int k = 0; k < 4; ++k) {
        const float y = (c[k] - mean) * inv * gam[k] + bet[k];
        o[k] = 0.5f * y * (1.f + erff(y * 0.70710678118f));
    }
    *((float4*)(out_g + (size_t)(row0 + row) * 64 + w4)) =
        make_float4(o[0], o[1], o[2], o[3]);
}

extern "C" void kernel_launch(void* const* d_in, const int* in_sizes, int n_in,
                              void* d_out, int out_size, void* d_ws, size_t ws_size,
                              hipStream_t stream) {
    (void)in_sizes; (void)n_in; (void)out_size;
    const bool pre = (ws_size >= (size_t)(64 * SLABF));
    if (pre) {
        kan_prep<<<976, 256, 0, stream>>>((const float*)d_in[3], (unsigned char*)d_ws);
        kan_fused<true><<<1024, NTHREADS, 0, stream>>>(
            (const float*)d_in[0], (const float*)d_in[1], (const float*)d_in[2],
            (const float*)d_in[3], (const float*)d_in[4], (const float*)d_in[5],
            (const float*)d_in[6], (const float*)d_in[7], (const float*)d_in[8],
            (const float*)d_in[9], (const unsigned char*)d_ws, (float*)d_out);
    } else {
        kan_fused<false><<<1024, NTHREADS, 0, stream>>>(
            (const float*)d_in[0], (const float*)d_in[1], (const float*)d_in[2],
            (const float*)d_in[3], (const float*)d_in[4], (const float*)d_in[5],
            (const float*)d_in[6], (const float*)d_in[7], (const float*)d_in[8],
            (const float*)d_in[9], (const unsigned char*)d_ws, (float*)d_out);
    }
}